// Round 1
// baseline (37.479 us; speedup 1.0000x reference)
//
#include <hip/hip_runtime.h>

// DGraFormer graph-propagation block, algebraically collapsed.
//
// Reference math per (b,s) slice, A = adj[b,s,:,:] (NxN, N=64):
//   h0 = x ⊗ w_start + 1 ⊗ b_start
//   h_{k+1} = beta*x ⊗ 1_d + (1-beta) * A^T h_k
//   out = sum_k <h_k, w_mlp[k*D:(k+1)*D]> + b_mlp
// Channel dim is rank-3 (basis {w_start, b_start, 1_d}), so with
//   y_k = ((1-b)A^T)^k x,  u_k = ((1-b)A^T)^k 1,  z_k = b*sum_{j<k} y_j
// we get out[n] = sum_k P'_k y_k[n] + sum_k Q_k u_k[n] + (Q_0 + b_mlp)
// where P_k = <w_start, wm_k>, Q_k = <b_start, wm_k>, R_k = sum(wm_k),
//   P'_0 = P_0 + b(R_1+R_2+R_3), P'_1 = P_1 + b(R_2+R_3), P'_2 = P_2 + b R_3, P'_3 = P_3.
// Only 6 matvecs (64x64) per (b,s). Memory-bound on one pass over adj (176 MB).

#define BB 32
#define NN 64
#define SS 336
#define DD 32
#define BETA 0.05f
#define OMB 0.95f

__global__ __launch_bounds__(256) void dgra_collapsed_kernel(
    const float* __restrict__ x, const float* __restrict__ adj,
    const float* __restrict__ w_start, const float* __restrict__ b_start,
    const float* __restrict__ w_mlp, const float* __restrict__ b_mlp,
    float* __restrict__ out)
{
    const int tid  = threadIdx.x;
    const int lane = tid & 63;
    const int w    = tid >> 6;           // wave id in block, 0..3
    const int blk  = blockIdx.x;
    const int b    = blk / (SS / 4);
    const int s4   = blk % (SS / 4);
    const int s    = s4 * 4 + w;

    // ---- fold MLP through the rank-3 basis (uniform scalar work) ----
    float P[4] = {0.f,0.f,0.f,0.f}, Q[4] = {0.f,0.f,0.f,0.f}, R[4] = {0.f,0.f,0.f,0.f};
#pragma unroll
    for (int d = 0; d < DD; ++d) {
        const float wd = w_start[d];
        const float bd = b_start[d];
#pragma unroll
        for (int k = 0; k < 4; ++k) {
            const float m = w_mlp[k * DD + d];
            P[k] = fmaf(wd, m, P[k]);
            Q[k] = fmaf(bd, m, Q[k]);
            R[k] += m;
        }
    }
    float Pp[4];
    Pp[0] = P[0] + BETA * (R[1] + R[2] + R[3]);
    Pp[1] = P[1] + BETA * (R[2] + R[3]);
    Pp[2] = P[2] + BETA * R[3];
    Pp[3] = P[3];
    const float c0 = Q[0] + b_mlp[0];

    // ---- stage A column `lane` into registers (coalesced: whole wave reads a row per instr) ----
    const float* Ab = adj + (size_t)(b * SS + s) * (NN * NN);
    float Areg[NN];
#pragma unroll
    for (int n = 0; n < NN; ++n)
        Areg[n] = Ab[n * NN + lane];     // adj[b, s, n, lane]

    float y = x[(size_t)(b * NN + lane) * SS + s];   // y_0
    float u = 1.0f;                                  // u_0
    float acc = fmaf(Pp[0], y, c0);

    __shared__ float2 yu[4][NN];         // per-wave broadcast buffer

#pragma unroll
    for (int k = 1; k <= 3; ++k) {
        yu[w][lane] = make_float2(y, u);
        __asm__ volatile("s_waitcnt lgkmcnt(0)" ::: "memory");  // wave-internal: writes visible to all 64 lanes
        float ys = 0.f, us = 0.f;
#pragma unroll
        for (int n = 0; n < NN; ++n) {
            const float2 t = yu[w][n];   // uniform address -> broadcast, conflict-free
            ys = fmaf(Areg[n], t.x, ys);
            us = fmaf(Areg[n], t.y, us);
        }
        y = OMB * ys;
        u = OMB * us;
        acc = fmaf(Pp[k], y, acc);
        acc = fmaf(Q[k], u, acc);
    }

    // ---- transpose through LDS so stores are float4-coalesced along s ----
    __shared__ __align__(16) float res[NN][4];
    res[lane][w] = acc;
    __syncthreads();
    if (w == 0) {
        const float4 v = *reinterpret_cast<const float4*>(res[lane]);
        *reinterpret_cast<float4*>(&out[(size_t)(b * NN + lane) * SS + s4 * 4]) = v;
    }
}

extern "C" void kernel_launch(void* const* d_in, const int* in_sizes, int n_in,
                              void* d_out, int out_size, void* d_ws, size_t ws_size,
                              hipStream_t stream) {
    const float* x       = (const float*)d_in[0];
    const float* adj     = (const float*)d_in[1];
    const float* w_start = (const float*)d_in[2];
    const float* b_start = (const float*)d_in[3];
    const float* w_mlp   = (const float*)d_in[4];
    const float* b_mlp   = (const float*)d_in[5];
    float* out = (float*)d_out;

    const int grid = BB * (SS / 4);      // 32 * 84 = 2688 blocks, 256 thr (4 waves)
    dgra_collapsed_kernel<<<grid, 256, 0, stream>>>(x, adj, w_start, b_start, w_mlp, b_mlp, out);
}